// Round 10
// baseline (71.839 us; speedup 1.0000x reference)
//
#include <hip/hip_runtime.h>
#include <math.h>

#define B 16
#define A 3
#define W 128
#define HW 16384          // 128*128
#define NCH 255
#define NCLS 80
#define NCAND 49152       // HW*A
#define K 100
#define NBINS 4096
#define CAP 1024

__device__ __forceinline__ float sigmoidf_(float v) {
    return 1.0f / (1.0f + expf(-v));
}

__device__ __forceinline__ bool pair_before(float sa, int ia, float sb, int ib) {
    // "a comes before b" in descending-score, ascending-index order
    return (sa > sb) || (sa == sb && ia < ib);
}

// ---- Kernel 1: pure-streaming masked score + class argmax -----------------
// grid: B*A*HW/8/256 = 384 blocks; each thread owns 8 consecutive hw cells
// (two independent float4 groups -> 2KB contiguous per wave per channel)
__global__ __launch_bounds__(256) void k_scores(const float* __restrict__ x,
                                                float* __restrict__ scores,
                                                unsigned char* __restrict__ labels) {
    int t = blockIdx.x * 256 + threadIdx.x;
    int b = t / (A * HW / 8);
    int r = t - b * (A * HW / 8);
    int a = r / (HW / 8);
    int q = r - a * (HW / 8);
    int hw = q * 8;
    const float* base = x + (size_t)(b * NCH + a * 85) * HW + hw;

    float4 o4a = *(const float4*)(base + 4 * HW);
    float4 o4b = *(const float4*)(base + 4 * HW + 4);
    float4 m4a = *(const float4*)(base + 5 * HW);
    float4 m4b = *(const float4*)(base + 5 * HW + 4);
    int ama[4] = {0, 0, 0, 0};
    int amb[4] = {0, 0, 0, 0};
    #pragma unroll
    for (int c = 1; c < NCLS; ++c) {
        float4 va = *(const float4*)(base + (size_t)(5 + c) * HW);
        float4 vb = *(const float4*)(base + (size_t)(5 + c) * HW + 4);
        bool g0 = va.x > m4a.x; ama[0] = g0 ? c : ama[0]; m4a.x = g0 ? va.x : m4a.x;
        bool g1 = va.y > m4a.y; ama[1] = g1 ? c : ama[1]; m4a.y = g1 ? va.y : m4a.y;
        bool g2 = va.z > m4a.z; ama[2] = g2 ? c : ama[2]; m4a.z = g2 ? va.z : m4a.z;
        bool g3 = va.w > m4a.w; ama[3] = g3 ? c : ama[3]; m4a.w = g3 ? va.w : m4a.w;
        bool h0 = vb.x > m4b.x; amb[0] = h0 ? c : amb[0]; m4b.x = h0 ? vb.x : m4b.x;
        bool h1 = vb.y > m4b.y; amb[1] = h1 ? c : amb[1]; m4b.y = h1 ? vb.y : m4b.y;
        bool h2 = vb.z > m4b.z; amb[2] = h2 ? c : amb[2]; m4b.z = h2 ? vb.z : m4b.z;
        bool h3 = vb.w > m4b.w; amb[3] = h3 ? c : amb[3]; m4b.w = h3 ? vb.w : m4b.w;
    }
    float ola[4] = {o4a.x, o4a.y, o4a.z, o4a.w};
    float mla[4] = {m4a.x, m4a.y, m4a.z, m4a.w};
    float olb[4] = {o4b.x, o4b.y, o4b.z, o4b.w};
    float mlb[4] = {m4b.x, m4b.y, m4b.z, m4b.w};
    float outa[4], outb[4];
    #pragma unroll
    for (int l = 0; l < 4; ++l) {
        float obj = sigmoidf_(ola[l]);
        float cls = sigmoidf_(mla[l]);     // sigmoid monotone: max(sig)=sig(max)
        float sc = obj * cls;
        bool valid = (obj >= 0.5f) && (sc >= 0.05f);
        outa[l] = valid ? sc : -1.0f;
        float objB = sigmoidf_(olb[l]);
        float clsB = sigmoidf_(mlb[l]);
        float scB = objB * clsB;
        bool validB = (objB >= 0.5f) && (scB >= 0.05f);
        outb[l] = validB ? scB : -1.0f;
    }
    // storage layout [b][a][hw] for coalesced I/O
    size_t off = (size_t)b * NCAND + a * HW + hw;
    *(float4*)(scores + off)     = make_float4(outa[0], outa[1], outa[2], outa[3]);
    *(float4*)(scores + off + 4) = make_float4(outb[0], outb[1], outb[2], outb[3]);
    *(uchar4*)(labels + off)     = make_uchar4((unsigned char)ama[0], (unsigned char)ama[1],
                                               (unsigned char)ama[2], (unsigned char)ama[3]);
    *(uchar4*)(labels + off + 4) = make_uchar4((unsigned char)amb[0], (unsigned char)amb[1],
                                               (unsigned char)amb[2], (unsigned char)amb[3]);
}

// ---- Kernel 2: per-image hist+select+compact+rank-topk+decode+NMS+write ---
__global__ __launch_bounds__(1024) void k_tail(const float* __restrict__ x,
                                               const float* __restrict__ anchors,
                                               const float* __restrict__ scores,
                                               const unsigned char* __restrict__ labels,
                                               float* __restrict__ out) {
    __shared__ unsigned int lh[NBINS];        // 16 KB
    __shared__ unsigned int suf[1024];        // 4 KB
    __shared__ int tstar, sh_thr;
    __shared__ unsigned int sh_cnt;
    __shared__ float cs[CAP];
    __shared__ int ci[CAP];
    __shared__ float ts[K];
    __shared__ int tix[K];
    __shared__ float bx[K][4];
    __shared__ float area[K];
    __shared__ int lab[K];
    __shared__ unsigned int sup[K][4];
    __shared__ unsigned int keepw[4];

    int b = blockIdx.x;
    int tid = threadIdx.x;
    const float* sb = scores + (size_t)b * NCAND;

    for (int i = tid; i < NBINS; i += 1024) lh[i] = 0;
    if (tid == 0) { tstar = -1; sh_thr = 0; sh_cnt = 0; }
    if (tid < 4) keepw[tid] = 0u;
    for (int i = tid; i < K * 4; i += 1024) ((unsigned int*)sup)[i] = 0u;
    if (tid < K) { ts[tid] = -3.0f; tix[tid] = 0x7FFFFFFF; }
    __syncthreads();

    // pass 1: histogram of valid scores (L2/L3-resident read)
    #pragma unroll
    for (int it = 0; it < 12; ++it) {
        int o = (it * 1024 + tid) * 4;
        float4 v = *(const float4*)(sb + o);
        float sv[4] = {v.x, v.y, v.z, v.w};
        #pragma unroll
        for (int l = 0; l < 4; ++l) {
            float s = sv[l];
            if (s > 0.0f) {
                int bin = (int)(s * (float)NBINS);
                bin = bin > NBINS - 1 ? NBINS - 1 : bin;
                atomicAdd(&lh[bin], 1u);
            }
        }
    }
    __syncthreads();

    // coarse (x4) suffix scan over 1024 entries
    unsigned int acc = lh[tid * 4] + lh[tid * 4 + 1] +
                       lh[tid * 4 + 2] + lh[tid * 4 + 3];
    suf[tid] = acc;
    __syncthreads();
    for (int off = 1; off < 1024; off <<= 1) {
        unsigned int add = (tid + off < 1024) ? suf[tid + off] : 0u;
        __syncthreads();
        suf[tid] += add;
        __syncthreads();
    }
    if (suf[tid] >= K && (tid == 1023 || suf[tid + 1] < K)) tstar = tid;
    __syncthreads();
    if (tid == 0 && tstar >= 0) {
        int t = tstar;
        unsigned int running = (t < 1023) ? suf[t + 1] : 0u;
        int result = t * 4;
        for (int bin = t * 4 + 3; bin >= t * 4; --bin) {
            running += lh[bin];
            if (running >= K) { result = bin; break; }
        }
        sh_thr = result;
    }
    __syncthreads();

    // pass 2: compact survivors (bin >= thr) into LDS
    int thr = sh_thr;
    #pragma unroll
    for (int it = 0; it < 12; ++it) {
        int o = (it * 1024 + tid) * 4;
        float4 v = *(const float4*)(sb + o);
        float sv[4] = {v.x, v.y, v.z, v.w};
        #pragma unroll
        for (int l = 0; l < 4; ++l) {
            float s = sv[l];
            if (s > 0.0f && (int)(s * (float)NBINS) >= thr) {
                unsigned int p = atomicAdd(&sh_cnt, 1u);
                if (p < CAP) {
                    int so = o + l;                 // storage offset a*HW+hw
                    int aa = so >> 14;
                    int hh = so & (HW - 1);
                    cs[p] = s;
                    ci[p] = hh * A + aa;            // reference flat index
                }
            }
        }
    }
    __syncthreads();
    int n = (int)sh_cnt; if (n > CAP) n = CAP;

    // one-pass rank select: rank = #pairs strictly before me
    if (tid < n) {
        float s0 = cs[tid]; int i0 = ci[tid];
        int rank = 0;
        for (int j = 0; j < n; ++j)
            rank += pair_before(cs[j], ci[j], s0, i0) ? 1 : 0;
        if (rank < K) { ts[rank] = s0; tix[rank] = i0; }
    }
    __syncthreads();

    // decode boxes + label for valid top-K
    if (tid < K && ts[tid] > 0.0f) {
        int nidx = tix[tid];
        int a = nidx % A;
        int hw = nidx / A;
        int cx = hw % W;
        int cy = hw / W;
        const float* base = x + (size_t)(b * NCH + a * 85) * HW + hw;
        float tx = base[0];
        float ty = base[HW];
        float tw = base[2 * HW];
        float th = base[3 * HW];
        float bcx = (sigmoidf_(tx) + (float)cx) / 128.0f;
        float bcy = (sigmoidf_(ty) + (float)cy) / 128.0f;
        float bw = fminf(fmaxf(expf(tw) * anchors[a * 2 + 0], 0.0f), 2.0f);
        float bh = fminf(fmaxf(expf(th) * anchors[a * 2 + 1], 0.0f), 2.0f);
        float x1 = bcx - 0.5f * bw;
        float y1 = bcy - 0.5f * bh;
        float x2 = x1 + bw;
        float y2 = y1 + bh;
        x1 = fminf(fmaxf(x1, 0.0f), 1.0f);
        y1 = fminf(fmaxf(y1, 0.0f), 1.0f);
        x2 = fminf(fmaxf(x2, 0.0f), 1.0f);
        y2 = fminf(fmaxf(y2, 0.0f), 1.0f);
        bx[tid][0] = x1; bx[tid][1] = y1; bx[tid][2] = x2; bx[tid][3] = y2;
        area[tid] = fmaxf(x2 - x1, 0.0f) * fmaxf(y2 - y1, 0.0f);
        lab[tid] = (int)labels[(size_t)b * NCAND + a * HW + hw];
        atomicOr(&keepw[tid >> 5], 1u << (tid & 31));
    }
    __syncthreads();

    // IoU suppression bitmasks (j > i, both valid)
    for (int p = tid; p < K * K; p += 1024) {
        int i = p / K, j = p % K;
        if (j > i && ts[i] > 0.0f && ts[j] > 0.0f) {
            float lx = fmaxf(bx[i][0], bx[j][0]);
            float ly = fmaxf(bx[i][1], bx[j][1]);
            float rx = fminf(bx[i][2], bx[j][2]);
            float ry = fminf(bx[i][3], bx[j][3]);
            float iw = fmaxf(rx - lx, 0.0f);
            float ih = fmaxf(ry - ly, 0.0f);
            float inter = iw * ih;
            float uni = area[i] + area[j] - inter;
            float iou = inter / fmaxf(uni, 1e-12f);
            if (iou > 0.7f) atomicOr(&sup[i][j >> 5], 1u << (j & 31));
        }
    }
    __syncthreads();

    // greedy scan (register bit-ops, one thread)
    if (tid == 0) {
        unsigned int kw0 = keepw[0], kw1 = keepw[1], kw2 = keepw[2], kw3 = keepw[3];
        for (int i = 0; i < K; ++i) {
            unsigned int kwi = (i < 32) ? kw0 : (i < 64) ? kw1 : (i < 96) ? kw2 : kw3;
            if ((kwi >> (i & 31)) & 1u) {
                kw0 &= ~sup[i][0];
                kw1 &= ~sup[i][1];
                kw2 &= ~sup[i][2];
                kw3 &= ~sup[i][3];
            }
        }
        keepw[0] = kw0; keepw[1] = kw1; keepw[2] = kw2; keepw[3] = kw3;
    }
    __syncthreads();

    // write outputs: boxes | scores | labels | keep (all float32, flat)
    if (tid < K) {
        int kp = (keepw[tid >> 5] >> (tid & 31)) & 1u;
        float sc = ts[tid];
        float* ob = out + (size_t)b * K * 4;
        float* osc = out + (size_t)B * K * 4;
        float* olab = osc + (size_t)B * K;
        float* okp = olab + (size_t)B * K;
        ob[tid * 4 + 0] = kp ? bx[tid][0] : 0.0f;
        ob[tid * 4 + 1] = kp ? bx[tid][1] : 0.0f;
        ob[tid * 4 + 2] = kp ? bx[tid][2] : 0.0f;
        ob[tid * 4 + 3] = kp ? bx[tid][3] : 0.0f;
        osc[b * K + tid] = kp ? sc : 0.0f;
        olab[b * K + tid] = kp ? (float)lab[tid] : -1.0f;
        okp[b * K + tid] = kp ? 1.0f : 0.0f;
    }
}

extern "C" void kernel_launch(void* const* d_in, const int* in_sizes, int n_in,
                              void* d_out, int out_size, void* d_ws, size_t ws_size,
                              hipStream_t stream) {
    const float* x = (const float*)d_in[0];
    const float* anchors = (const float*)d_in[1];
    float* out = (float*)d_out;

    float* scores = (float*)d_ws;                                       // B*NCAND f32 (3 MB)
    unsigned char* labels = (unsigned char*)(scores + (size_t)B * NCAND); // B*NCAND u8

    k_scores<<<(B * A * HW / 8) / 256, 256, 0, stream>>>(x, scores, labels);
    k_tail<<<B, 1024, 0, stream>>>(x, anchors, scores, labels, out);
}